// Round 15
// baseline (2053.284 us; speedup 1.0000x reference)
//
#include <hip/hip_runtime.h>
#include <cstdint>

#define NPIX 16384
#define KNN 8
#define PW 130                 // padded width/height
#define NPPAD (PW * PW)        // padded positions: 16900
#define PLANE (NPPAD * 16)     // floats per 16-channel phase plane
#define QC 37                  // LDS quads per candidate (36 real + 1 pad; stride 148 dwords = 20 mod 32 -> conflict-free)

typedef float f32x4 __attribute__((ext_vector_type(4)));
typedef __attribute__((address_space(3))) uint32_t lds_u32_t;
typedef const __attribute__((address_space(1))) uint32_t glob_u32_t;

// ---------------- Threefry-2x32 (exact JAX semantics: 20 rounds) ----------------
__host__ __device__ __forceinline__ void tf2x32(uint32_t k0, uint32_t k1,
                                                uint32_t x0, uint32_t x1,
                                                uint32_t& o0, uint32_t& o1) {
  uint32_t ks2 = k0 ^ k1 ^ 0x1BD11BDAu;
  x0 += k0; x1 += k1;
#define TFR(r) { x0 += x1; x1 = (x1 << r) | (x1 >> (32 - r)); x1 ^= x0; }
  TFR(13) TFR(15) TFR(26) TFR(6)  x0 += k1;  x1 += ks2 + 1u;
  TFR(17) TFR(29) TFR(16) TFR(24) x0 += ks2; x1 += k0 + 2u;
  TFR(13) TFR(15) TFR(26) TFR(6)  x0 += k0;  x1 += k1 + 3u;
  TFR(17) TFR(29) TFR(16) TFR(24) x0 += k1;  x1 += ks2 + 4u;
  TFR(13) TFR(15) TFR(26) TFR(6)  x0 += ks2; x1 += k0 + 5u;
#undef TFR
  o0 = x0; o1 = x1;
}

// partitionable-threefry random_bits (32-bit): element j -> w0^w1 of TF(key,(0,j))
__device__ __forceinline__ uint32_t rbits32(uint32_t ka, uint32_t kb, uint32_t j) {
  uint32_t o0, o1;
  tf2x32(ka, kb, 0u, j, o0, o1);
  return o0 ^ o1;
}

// randint element draw; K = (k1a,k1b,k2a,k2b) = foldlike-split of randint key
__device__ __forceinline__ int rnd_int(uint4 K, uint32_t j, uint32_t span,
                                       uint32_t mult, int minv) {
  uint32_t hi = rbits32(K.x, K.y, j);
  uint32_t lo = rbits32(K.z, K.w, j);
  uint32_t off = ((hi % span) * mult + (lo % span)) % span;
  return minv + (int)off;
}

// ---------------- per-lane patch SSD cost (init only), [2][130][130][16] --------
// Bit-exact channel-ascending (ch = hh*16+cc*4+j), positions-inner accumulation.
__device__ __forceinline__ float cost_eval_pl(const float* __restrict__ apt,
                                              const float* __restrict__ bpt,
                                              int py0, int px0, int sy, int sx) {
  float acc = 0.f;
#pragma unroll
  for (int hh = 0; hh < 2; ++hh) {
    const float* ab = apt + (size_t)hh * PLANE + (size_t)(py0 * PW + px0) * 16;
    const float* bb = bpt + (size_t)hh * PLANE + (size_t)(sy * PW + sx) * 16;
#pragma unroll
    for (int cc = 0; cc < 4; ++cc) {
      f32x4 av[9], bv[9];
#pragma unroll
      for (int p = 0; p < 9; ++p) {
        int dy = p / 3, dx = p - dy * 3;
        av[p] = *(const f32x4*)(ab + (dy * PW + dx) * 16 + cc * 4);
        bv[p] = *(const f32x4*)(bb + (dy * PW + dx) * 16 + cc * 4);
      }
#pragma unroll
      for (int j = 0; j < 4; ++j) {
#pragma unroll
        for (int p = 0; p < 9; ++p) {
          float d = __fsub_rn(av[p][j], bv[p][j]);
          acc = __fadd_rn(acc, __fmul_rn(d, d));
        }
      }
    }
  }
  return acc;
}

// ---------------- pad + transpose a,b to [2][130][130][16] ----------------------
__global__ __launch_bounds__(256) void pad_kernel(
    const float* __restrict__ a, const float* __restrict__ b,
    float* __restrict__ apt, float* __restrict__ bpt) {
  int t = (int)(blockIdx.x * blockDim.x + threadIdx.x);
  if (t >= 32 * NPPAD) return;
  int lo = t & 15;
  int rest = t >> 4;
  int pos = rest % NPPAD;
  int hh = rest / NPPAD;
  int c = hh * 16 + lo;
  int py = pos / PW, px = pos % PW;
  int y = py - 1; y = y < 0 ? 0 : (y > 127 ? 127 : y);
  int x = px - 1; x = x < 0 ? 0 : (x > 127 ? 127 : x);
  int src = (c << 14) + (y << 7) + x;
  apt[t] = a[src];
  bpt[t] = b[src];
}

// ---------------- init: random shifts + their costs (full-wave) -----------------
__global__ __launch_bounds__(256) void init_kernel(
    const float* __restrict__ apt, const float* __restrict__ bpt,
    uint32_t* __restrict__ npack, float* __restrict__ ncost, uint4 IK) {
  int t = (int)(blockIdx.x * blockDim.x + threadIdx.x);  // 8*16384
  int pix = t & (NPIX - 1);
  int s = t >> 14;
  int py0 = pix >> 7, px0 = pix & 127;
  uint32_t j0 = (uint32_t)(s * 2) * 16384u + (uint32_t)pix;
  int sy = rnd_int(IK, j0, 128u, 0u, 0);
  int sx = rnd_int(IK, j0 + 16384u, 128u, 0u, 0);
  float cst = cost_eval_pl(apt, bpt, py0, px0, sy, sx);
  npack[t] = (uint32_t)((sy << 7) | sx);
  ncost[t] = cst;
}

// ---------------- one PatchMatch iteration --------------------------------------
// 16-ch-last layout: a candidate's phase patch = 3 rows x 192B, every position a
// full 64B line -> 18 line-visits/candidate total (optimal). b staged via
// global_load_lds into one 37888 B buffer (QC=37 slots/cand: 36 real + 1 pad so
// eval read stride 37 quads is bank-conflict-free). a read directly from global
// with wave-uniform addresses -> compiler scalarizes to s_load (no DS traffic).
__global__ __launch_bounds__(64, 4) void step_kernel(
    const float* __restrict__ apt, const float* __restrict__ bpt,
    const uint32_t* __restrict__ ppack, const float* __restrict__ pcost,
    uint32_t* __restrict__ npack, float* __restrict__ ncost,
    uint4 K0, uint4 K1, uint4 K2, uint4 K3) {
  __shared__ f32x4 ldsb[64 * QC];      // 37888 B single buffer for b
  int bidx = (int)blockIdx.x;
  int pix = ((bidx & 7) << 11) | (bidx >> 3);   // XCD-contiguous remap (16384 = 8*2048)
  int lane = (int)threadIdx.x;
  int py0 = pix >> 7, px0 = pix & 127;
  int g = lane >> 3, s = lane & 7;

  uint32_t old_pack = 0u; float old_cost_f = 0.f;
  if (lane < 8) {
    old_pack = ppack[lane * NPIX + pix];
    old_cost_f = pcost[lane * NPIX + pix];
  }

  // candidate generation; order matches all_s = [old8, left8, right8, up8, down8, r0..r3]
  int sy, sx;
  if (g < 4) {
    int nh = py0, nw = px0, dsy = 0, dsx = 0;
    if (g == 0)      { nw = (px0 + 127) & 127; dsx = 1;  }
    else if (g == 1) { nw = (px0 + 1) & 127;   dsx = -1; }
    else if (g == 2) { nh = (py0 + 127) & 127; dsy = 1;  }
    else             { nh = (py0 + 1) & 127;   dsy = -1; }
    uint32_t p = ppack[s * NPIX + (nh << 7) + nw];
    sy = (int)(p >> 7) + dsy;
    sx = (int)(p & 127u) + dsx;
  } else {
    uint32_t p = ppack[s * NPIX + pix];
    uint4 Ki      = (g == 4) ? K0   : (g == 5) ? K1  : (g == 6) ? K2 : K3;
    uint32_t span = (g == 4) ? 129u : (g == 5) ? 33u : (g == 6) ? 9u : 3u;
    uint32_t mult = (g == 4) ? 16u  : (g == 5) ? 4u  : (g == 6) ? 4u : 1u;
    int minv      = (g == 4) ? -64  : (g == 5) ? -16 : (g == 6) ? -4 : -1;
    uint32_t j0 = (uint32_t)(s * 2) * 16384u + (uint32_t)pix;
    sy = (int)(p >> 7)   + rnd_int(Ki, j0, span, mult, minv);
    sx = (int)(p & 127u) + rnd_int(Ki, j0 + 16384u, span, mult, minv);
  }
  sy = sy < 0 ? 0 : (sy > 127 ? 127 : sy);
  sx = sx < 0 ? 0 : (sx > 127 ? 127 : sx);
  uint32_t cnd_pack = (uint32_t)((sy << 7) | sx);

  // ---- staging: flat quad f = i*64+lane over (candidate c = f/QC, slot q);
  // q<36: quad (position p = q>>2, ch-quad cc = q&3) of c's patch -- consecutive
  // q = consecutive 16B in memory (rows of 192B) -> 4 lanes share each 64B line.
  // q==36: pad slot, loads a fixed line. Descriptors recomputed per GLB to keep
  // VGPR pressure low (values are phase-independent except the plane offset).
#define GLB(PH)                                                             \
  _Pragma("unroll")                                                         \
  for (int i = 0; i < QC; ++i) {                                            \
    int f = i * 64 + lane;                                                  \
    int c = f / QC, q = f - c * QC;                                         \
    uint32_t pk = (uint32_t)__shfl((int)cnd_pack, c);                       \
    int off = 0;                                                            \
    if (q < 36) {                                                           \
      int p = q >> 2, cc = q & 3;                                           \
      int dy = p / 3, dx = p - dy * 3;                                      \
      off = (((int)(pk >> 7) + dy) * PW + (int)(pk & 127u) + dx) * 16       \
            + cc * 4;                                                       \
    }                                                                       \
    __builtin_amdgcn_global_load_lds(                                       \
        (glob_u32_t*)(bpt + (size_t)(PH) * PLANE + off),                    \
        (lds_u32_t*)&ldsb[i * 64], 16, 0, 0);                               \
  }

  GLB(0)

  // ---- 2 phases of 16 channels; accumulation ch = hh*16+cc*4+j ascending,
  // positions inner -> bit-identical to reference. a-values read straight from
  // global via uniform addresses (SMEM path).
  float acc = 0.f;

#define PHASE(HH, DO_NEXT)                                                  \
  asm volatile("s_waitcnt vmcnt(0)" ::: "memory");                          \
  {                                                                         \
    const float* ab = apt + (size_t)(HH) * PLANE                            \
                     + (size_t)(py0 * PW + px0) * 16;                       \
    _Pragma("unroll")                                                       \
    for (int cc = 0; cc < 4; ++cc) {                                        \
      f32x4 av[9], bv[9];                                                   \
      _Pragma("unroll")                                                     \
      for (int p = 0; p < 9; ++p) {                                         \
        int dy = p / 3, dx = p - dy * 3;                                    \
        bv[p] = ldsb[lane * QC + p * 4 + cc];                               \
        av[p] = *(const f32x4*)(ab + (dy * PW + dx) * 16 + cc * 4);         \
      }                                                                     \
      if (cc == 3) {                                                        \
        asm volatile("s_waitcnt lgkmcnt(0)" ::: "memory");                  \
        DO_NEXT                                                             \
      }                                                                     \
      _Pragma("unroll")                                                     \
      for (int j = 0; j < 4; ++j) {                                         \
        _Pragma("unroll")                                                   \
        for (int p = 0; p < 9; ++p) {                                       \
          float d = __fsub_rn(av[p][j], bv[p][j]);                          \
          acc = __fadd_rn(acc, __fmul_rn(d, d));                            \
        }                                                                   \
      }                                                                     \
    }                                                                       \
  }

  PHASE(0, GLB(1))
  PHASE(1, )
#undef PHASE
#undef GLB

  float cnd_cost = acc;

  // stable top-8 (ascending cost, ties -> lower candidate idx), matching
  // lax.top_k. SELECT and EXTRACT fused per round to minimize live registers.
  unsigned long long new_key =
      ((unsigned long long)__float_as_uint(cnd_cost) << 32) | (unsigned)(8 + lane);
  unsigned long long old_key = (lane < 8)
      ? (((unsigned long long)__float_as_uint(old_cost_f) << 32) | (unsigned)lane)
      : ~0ull;
  bool new_used = false, old_used = (lane >= 8);

  uint32_t out_pack = 0u; float out_cost = 0.f;
#define TOPK_ROUND(R)                                                      \
  {                                                                        \
    unsigned long long kmin = new_used ? ~0ull : new_key;                  \
    if (!old_used && old_key < kmin) kmin = old_key;                       \
    _Pragma("unroll")                                                      \
    for (int off = 32; off; off >>= 1) {                                   \
      unsigned long long o = __shfl_xor(kmin, off);                        \
      if (o < kmin) kmin = o;                                              \
    }                                                                      \
    if (!new_used && new_key == kmin) new_used = true;                     \
    else if (!old_used && old_key == kmin) old_used = true;                \
    uint32_t idx = (uint32_t)kmin;                                         \
    float cst = __uint_as_float((uint32_t)(kmin >> 32));                   \
    int srcOld = (idx < 8u) ? (int)idx : 0;                                \
    int srcNew = (idx >= 8u) ? (int)(idx - 8u) : 0;                        \
    uint32_t po = __shfl(old_pack, srcOld);                                \
    uint32_t pn = __shfl(cnd_pack, srcNew);                                \
    uint32_t pk = (idx < 8u) ? po : pn;                                    \
    if (lane == R) { out_pack = pk; out_cost = cst; }                      \
  }
  TOPK_ROUND(0) TOPK_ROUND(1) TOPK_ROUND(2) TOPK_ROUND(3)
  TOPK_ROUND(4) TOPK_ROUND(5) TOPK_ROUND(6) TOPK_ROUND(7)
#undef TOPK_ROUND

  if (lane < 8) {
    npack[lane * NPIX + pix] = out_pack;
    ncost[lane * NPIX + pix] = out_cost;
  }
}

// ---------------- softmax weights over 8 costs ----------------------------------
__global__ __launch_bounds__(256) void weights_kernel(
    const float* __restrict__ cost0, float* __restrict__ wbuf) {
  int pix = (int)(blockIdx.x * blockDim.x + threadIdx.x);
  if (pix >= NPIX) return;
  float c[KNN];
  float m = 3.4e38f;
#pragma unroll
  for (int s = 0; s < KNN; ++s) { c[s] = cost0[s * NPIX + pix]; m = fminf(m, c[s]); }
  float e[KNN]; float sum = 0.f;
#pragma unroll
  for (int s = 0; s < KNN; ++s) { e[s] = expf(m - c[s]); sum += e[s]; }
  float inv = 1.f / sum;
#pragma unroll
  for (int s = 0; s < KNN; ++s) wbuf[s * NPIX + pix] = e[s] * inv;
}

// ---------------- weighted gather of v ------------------------------------------
__global__ __launch_bounds__(256) void out_kernel(
    const float* __restrict__ v, const uint32_t* __restrict__ pack0,
    const float* __restrict__ wbuf, float* __restrict__ out) {
  int t = (int)(blockIdx.x * blockDim.x + threadIdx.x);  // 4*64*128*128 threads
  int pix = t & (NPIX - 1);
  int ch = t >> 14;  // n*64 + c2
  const float* vc = v + ((size_t)ch << 14);
  float acc = 0.f;
#pragma unroll
  for (int s = 0; s < KNN; ++s) {
    uint32_t p = pack0[s * NPIX + pix];   // p == sy*128+sx
    float wgt = wbuf[s * NPIX + pix];
    acc = fmaf(wgt, vc[p], acc);
  }
  out[t] = acc;
}

// ---------------- host helpers ---------------------------------------------------
// foldlike split (jax_threefry_partitionable=True): key_i = TF(key, (0, i))
static void h_split_fl(uint32_t ka, uint32_t kb, uint32_t o[4]) {
  tf2x32(ka, kb, 0u, 0u, o[0], o[1]);  // keys[0]
  tf2x32(ka, kb, 0u, 1u, o[2], o[3]);  // keys[1]
}

extern "C" void kernel_launch(void* const* d_in, const int* in_sizes, int n_in,
                              void* d_out, int out_size, void* d_ws, size_t ws_size,
                              hipStream_t stream) {
  const float* q = (const float*)d_in[0];  // (1,32,128,128)
  const float* k = (const float*)d_in[1];  // (1,32,128,128)
  const float* v = (const float*)d_in[2];  // (4,64,128,128)
  float* out = (float*)d_out;

  uint32_t* ws = (uint32_t*)d_ws;
  uint32_t* pk[2] = { ws, ws + (size_t)KNN * NPIX };
  float* ct[2] = { (float*)(ws + (size_t)2 * KNN * NPIX),
                   (float*)(ws + (size_t)3 * KNN * NPIX) };
  float* wbuf = (float*)(ws + (size_t)4 * KNN * NPIX);
  float* apt  = (float*)(ws + (size_t)5 * KNN * NPIX);
  float* bpt  = apt + (size_t)32 * NPPAD;

  // key chain on host (pure arithmetic; graph-capture safe, deterministic)
  uint32_t sp[4];
  h_split_fl(0u, 42u, sp);                      // split(key(42)) [foldlike]
  uint32_t k0a = sp[0], k0b = sp[1];            // k0  (initial randint key)
  uint32_t kMa = sp[2], kMb = sp[3];            // key (closed over by scan body)

  pad_kernel<<<(32 * NPPAD + 255) / 256, 256, 0, stream>>>(q, k, apt, bpt);

  uint32_t ik[4];
  h_split_fl(k0a, k0b, ik);                     // randint's internal split of k0
  init_kernel<<<(KNN * NPIX) / 256, 256, 0, stream>>>(apt, bpt, pk[0], ct[0],
                                        make_uint4(ik[0], ik[1], ik[2], ik[3]));

  for (int it = 0; it < 10; ++it) {
    uint32_t ka, kb;
    tf2x32(kMa, kMb, 0u, (uint32_t)it, ka, kb); // kk = fold_in(key, it)
    uint4 K[4];
    for (int i = 0; i < 4; ++i) {
      uint32_t ia, ib;
      tf2x32(ka, kb, 0u, (uint32_t)i, ia, ib);  // ki = fold_in(kk, i)
      uint32_t o[4];
      h_split_fl(ia, ib, o);                    // randint's internal split of ki
      K[i] = make_uint4(o[0], o[1], o[2], o[3]);
    }
    step_kernel<<<NPIX, 64, 0, stream>>>(apt, bpt, pk[it & 1], ct[it & 1],
                                         pk[(it + 1) & 1], ct[(it + 1) & 1],
                                         K[0], K[1], K[2], K[3]);
  }

  weights_kernel<<<NPIX / 256, 256, 0, stream>>>(ct[0], wbuf);
  out_kernel<<<(4 * 64 * NPIX) / 256, 256, 0, stream>>>(v, pk[0], wbuf, out);
}

// Round 16
// 1892.378 us; speedup vs baseline: 1.0850x; 1.0850x over previous
//
#include <hip/hip_runtime.h>
#include <cstdint>

#define NPIX 16384
#define KNN 8
#define PW 130                 // padded width/height
#define NPPAD (PW * PW)        // padded positions: 16900
#define PLANE (NPPAD * 16)     // floats per 16-channel half plane

typedef float f32x4 __attribute__((ext_vector_type(4)));

// ---------------- Threefry-2x32 (exact JAX semantics: 20 rounds) ----------------
__host__ __device__ __forceinline__ void tf2x32(uint32_t k0, uint32_t k1,
                                                uint32_t x0, uint32_t x1,
                                                uint32_t& o0, uint32_t& o1) {
  uint32_t ks2 = k0 ^ k1 ^ 0x1BD11BDAu;
  x0 += k0; x1 += k1;
#define TFR(r) { x0 += x1; x1 = (x1 << r) | (x1 >> (32 - r)); x1 ^= x0; }
  TFR(13) TFR(15) TFR(26) TFR(6)  x0 += k1;  x1 += ks2 + 1u;
  TFR(17) TFR(29) TFR(16) TFR(24) x0 += ks2; x1 += k0 + 2u;
  TFR(13) TFR(15) TFR(26) TFR(6)  x0 += k0;  x1 += k1 + 3u;
  TFR(17) TFR(29) TFR(16) TFR(24) x0 += k1;  x1 += ks2 + 4u;
  TFR(13) TFR(15) TFR(26) TFR(6)  x0 += ks2; x1 += k0 + 5u;
#undef TFR
  o0 = x0; o1 = x1;
}

// partitionable-threefry random_bits (32-bit): element j -> w0^w1 of TF(key,(0,j))
__device__ __forceinline__ uint32_t rbits32(uint32_t ka, uint32_t kb, uint32_t j) {
  uint32_t o0, o1;
  tf2x32(ka, kb, 0u, j, o0, o1);
  return o0 ^ o1;
}

// randint element draw; K = (k1a,k1b,k2a,k2b) = foldlike-split of randint key
__device__ __forceinline__ int rnd_int(uint4 K, uint32_t j, uint32_t span,
                                       uint32_t mult, int minv) {
  uint32_t hi = rbits32(K.x, K.y, j);
  uint32_t lo = rbits32(K.z, K.w, j);
  uint32_t off = ((hi % span) * mult + (lo % span)) % span;
  return minv + (int)off;
}

// ---------------- per-lane patch SSD cost, [2][130][130][16] layout -------------
// Bit-exact channel-ascending (ch = hh*16+cc*4+j), positions-inner accumulation.
__device__ __forceinline__ float cost_eval_pl(const float* __restrict__ apt,
                                              const float* __restrict__ bpt,
                                              int py0, int px0, int sy, int sx) {
  float acc = 0.f;
#pragma unroll
  for (int hh = 0; hh < 2; ++hh) {
    const float* ab = apt + (size_t)hh * PLANE + (size_t)(py0 * PW + px0) * 16;
    const float* bb = bpt + (size_t)hh * PLANE + (size_t)(sy * PW + sx) * 16;
#pragma unroll
    for (int cc = 0; cc < 4; ++cc) {
      f32x4 av[9], bv[9];
#pragma unroll
      for (int p = 0; p < 9; ++p) {
        int dy = p / 3, dx = p - dy * 3;
        av[p] = *(const f32x4*)(ab + (dy * PW + dx) * 16 + cc * 4);
        bv[p] = *(const f32x4*)(bb + (dy * PW + dx) * 16 + cc * 4);
      }
#pragma unroll
      for (int j = 0; j < 4; ++j) {
#pragma unroll
        for (int p = 0; p < 9; ++p) {
          float d = __fsub_rn(av[p][j], bv[p][j]);
          acc = __fadd_rn(acc, __fmul_rn(d, d));
        }
      }
    }
  }
  return acc;
}

// ---------------- pad + transpose a,b to [2][130][130][16] ----------------------
__global__ __launch_bounds__(256) void pad_kernel(
    const float* __restrict__ a, const float* __restrict__ b,
    float* __restrict__ apt, float* __restrict__ bpt) {
  int t = (int)(blockIdx.x * blockDim.x + threadIdx.x);
  if (t >= 32 * NPPAD) return;
  int lo = t & 15;
  int rest = t >> 4;
  int pos = rest % NPPAD;
  int hh = rest / NPPAD;
  int c = hh * 16 + lo;
  int py = pos / PW, px = pos % PW;
  int y = py - 1; y = y < 0 ? 0 : (y > 127 ? 127 : y);
  int x = px - 1; x = x < 0 ? 0 : (x > 127 ? 127 : x);
  int src = (c << 14) + (y << 7) + x;
  apt[t] = a[src];
  bpt[t] = b[src];
}

// ---------------- init: random shifts + their costs (full-wave) -----------------
__global__ __launch_bounds__(256) void init_kernel(
    const float* __restrict__ apt, const float* __restrict__ bpt,
    uint32_t* __restrict__ npack, float* __restrict__ ncost, uint4 IK) {
  int t = (int)(blockIdx.x * blockDim.x + threadIdx.x);  // 8*16384
  int pix = t & (NPIX - 1);
  int s = t >> 14;
  int py0 = pix >> 7, px0 = pix & 127;
  uint32_t j0 = (uint32_t)(s * 2) * 16384u + (uint32_t)pix;
  int sy = rnd_int(IK, j0, 128u, 0u, 0);
  int sx = rnd_int(IK, j0 + 16384u, 128u, 0u, 0);
  float cst = cost_eval_pl(apt, bpt, py0, px0, sy, sx);
  npack[t] = (uint32_t)((sy << 7) | sx);
  ncost[t] = cst;
}

// ---------------- one PatchMatch iteration (per-lane gather, NO LDS) ------------
// Cross-round model: per-step wall tracks total memory-instruction count through
// the CU's shared issue path (~10 cy/instr): staged designs pay ~290/wave
// (TA + DS both ways) -> 75 us plateau. Per-lane gather pays 144 (72 b-gathers +
// 72 wave-uniform a-loads), zero DS. 16ch-last layout makes each position one
// aligned 64B line; lane-local cc-reuse hits L1/L2 (b fits per-XCD L2).
__global__ __launch_bounds__(64, 4) void step_kernel(
    const float* __restrict__ apt, const float* __restrict__ bpt,
    const uint32_t* __restrict__ ppack, const float* __restrict__ pcost,
    uint32_t* __restrict__ npack, float* __restrict__ ncost,
    uint4 K0, uint4 K1, uint4 K2, uint4 K3) {
  int bidx = (int)blockIdx.x;
  int pix = ((bidx & 7) << 11) | (bidx >> 3);   // XCD-contiguous remap (16384 = 8*2048)
  int lane = (int)threadIdx.x;
  int py0 = pix >> 7, px0 = pix & 127;
  int g = lane >> 3, s = lane & 7;

  uint32_t old_pack = 0u; float old_cost_f = 0.f;
  if (lane < 8) {
    old_pack = ppack[lane * NPIX + pix];
    old_cost_f = pcost[lane * NPIX + pix];
  }

  // candidate generation; order matches all_s = [old8, left8, right8, up8, down8, r0..r3]
  int sy, sx;
  if (g < 4) {
    int nh = py0, nw = px0, dsy = 0, dsx = 0;
    if (g == 0)      { nw = (px0 + 127) & 127; dsx = 1;  }
    else if (g == 1) { nw = (px0 + 1) & 127;   dsx = -1; }
    else if (g == 2) { nh = (py0 + 127) & 127; dsy = 1;  }
    else             { nh = (py0 + 1) & 127;   dsy = -1; }
    uint32_t p = ppack[s * NPIX + (nh << 7) + nw];
    sy = (int)(p >> 7) + dsy;
    sx = (int)(p & 127u) + dsx;
  } else {
    uint32_t p = ppack[s * NPIX + pix];
    uint4 Ki      = (g == 4) ? K0   : (g == 5) ? K1  : (g == 6) ? K2 : K3;
    uint32_t span = (g == 4) ? 129u : (g == 5) ? 33u : (g == 6) ? 9u : 3u;
    uint32_t mult = (g == 4) ? 16u  : (g == 5) ? 4u  : (g == 6) ? 4u : 1u;
    int minv      = (g == 4) ? -64  : (g == 5) ? -16 : (g == 6) ? -4 : -1;
    uint32_t j0 = (uint32_t)(s * 2) * 16384u + (uint32_t)pix;
    sy = (int)(p >> 7)   + rnd_int(Ki, j0, span, mult, minv);
    sx = (int)(p & 127u) + rnd_int(Ki, j0 + 16384u, span, mult, minv);
  }
  sy = sy < 0 ? 0 : (sy > 127 ? 127 : sy);
  sx = sx < 0 ? 0 : (sx > 127 ? 127 : sx);
  uint32_t cnd_pack = (uint32_t)((sy << 7) | sx);

  // a-base is wave-uniform (blockIdx-derived); force it into SGPRs so the
  // compiler can use scalar loads / single-line requests for av.
  {
    // nothing: py0/px0 already uniform, but make the pointer provably uniform
  }
  const float* ab0 = apt + (size_t)(py0 * PW + px0) * 16;
  uint64_t ap64 = (uint64_t)(uintptr_t)ab0;
  uint32_t alo = __builtin_amdgcn_readfirstlane((uint32_t)ap64);
  uint32_t ahi = __builtin_amdgcn_readfirstlane((uint32_t)(ap64 >> 32));
  const float* abu = (const float*)(uintptr_t)(((uint64_t)ahi << 32) | alo);
  const float* bb0 = bpt + (size_t)(sy * PW + sx) * 16;

  // ---- cost: per-lane eval, bit-exact ch = hh*16+cc*4+j ascending, pos inner.
  float acc = 0.f;
#pragma unroll
  for (int hh = 0; hh < 2; ++hh) {
    const float* ab = abu + (size_t)hh * PLANE;
    const float* bb = bb0 + (size_t)hh * PLANE;
#pragma unroll
    for (int cc = 0; cc < 4; ++cc) {
      f32x4 av[9], bv[9];
#pragma unroll
      for (int p = 0; p < 9; ++p) {
        int dy = p / 3, dx = p - dy * 3;
        bv[p] = *(const f32x4*)(bb + (dy * PW + dx) * 16 + cc * 4);
        av[p] = *(const f32x4*)(ab + (dy * PW + dx) * 16 + cc * 4);
      }
#pragma unroll
      for (int j = 0; j < 4; ++j) {
#pragma unroll
        for (int p = 0; p < 9; ++p) {
          float d = __fsub_rn(av[p][j], bv[p][j]);
          acc = __fadd_rn(acc, __fmul_rn(d, d));
        }
      }
    }
  }
  float cnd_cost = acc;

  // stable top-8 (ascending cost, ties -> lower candidate idx), matching
  // lax.top_k. SELECT and EXTRACT fused per round to minimize live registers.
  unsigned long long new_key =
      ((unsigned long long)__float_as_uint(cnd_cost) << 32) | (unsigned)(8 + lane);
  unsigned long long old_key = (lane < 8)
      ? (((unsigned long long)__float_as_uint(old_cost_f) << 32) | (unsigned)lane)
      : ~0ull;
  bool new_used = false, old_used = (lane >= 8);

  uint32_t out_pack = 0u; float out_cost = 0.f;
#define TOPK_ROUND(R)                                                      \
  {                                                                        \
    unsigned long long kmin = new_used ? ~0ull : new_key;                  \
    if (!old_used && old_key < kmin) kmin = old_key;                       \
    _Pragma("unroll")                                                      \
    for (int off = 32; off; off >>= 1) {                                   \
      unsigned long long o = __shfl_xor(kmin, off);                        \
      if (o < kmin) kmin = o;                                              \
    }                                                                      \
    if (!new_used && new_key == kmin) new_used = true;                     \
    else if (!old_used && old_key == kmin) old_used = true;                \
    uint32_t idx = (uint32_t)kmin;                                         \
    float cst = __uint_as_float((uint32_t)(kmin >> 32));                   \
    int srcOld = (idx < 8u) ? (int)idx : 0;                                \
    int srcNew = (idx >= 8u) ? (int)(idx - 8u) : 0;                        \
    uint32_t po = __shfl(old_pack, srcOld);                                \
    uint32_t pn = __shfl(cnd_pack, srcNew);                                \
    uint32_t pk = (idx < 8u) ? po : pn;                                    \
    if (lane == R) { out_pack = pk; out_cost = cst; }                      \
  }
  TOPK_ROUND(0) TOPK_ROUND(1) TOPK_ROUND(2) TOPK_ROUND(3)
  TOPK_ROUND(4) TOPK_ROUND(5) TOPK_ROUND(6) TOPK_ROUND(7)
#undef TOPK_ROUND

  if (lane < 8) {
    npack[lane * NPIX + pix] = out_pack;
    ncost[lane * NPIX + pix] = out_cost;
  }
}

// ---------------- softmax weights over 8 costs ----------------------------------
__global__ __launch_bounds__(256) void weights_kernel(
    const float* __restrict__ cost0, float* __restrict__ wbuf) {
  int pix = (int)(blockIdx.x * blockDim.x + threadIdx.x);
  if (pix >= NPIX) return;
  float c[KNN];
  float m = 3.4e38f;
#pragma unroll
  for (int s = 0; s < KNN; ++s) { c[s] = cost0[s * NPIX + pix]; m = fminf(m, c[s]); }
  float e[KNN]; float sum = 0.f;
#pragma unroll
  for (int s = 0; s < KNN; ++s) { e[s] = expf(m - c[s]); sum += e[s]; }
  float inv = 1.f / sum;
#pragma unroll
  for (int s = 0; s < KNN; ++s) wbuf[s * NPIX + pix] = e[s] * inv;
}

// ---------------- weighted gather of v ------------------------------------------
__global__ __launch_bounds__(256) void out_kernel(
    const float* __restrict__ v, const uint32_t* __restrict__ pack0,
    const float* __restrict__ wbuf, float* __restrict__ out) {
  int t = (int)(blockIdx.x * blockDim.x + threadIdx.x);  // 4*64*128*128 threads
  int pix = t & (NPIX - 1);
  int ch = t >> 14;  // n*64 + c2
  const float* vc = v + ((size_t)ch << 14);
  float acc = 0.f;
#pragma unroll
  for (int s = 0; s < KNN; ++s) {
    uint32_t p = pack0[s * NPIX + pix];   // p == sy*128+sx
    float wgt = wbuf[s * NPIX + pix];
    acc = fmaf(wgt, vc[p], acc);
  }
  out[t] = acc;
}

// ---------------- host helpers ---------------------------------------------------
// foldlike split (jax_threefry_partitionable=True): key_i = TF(key, (0, i))
static void h_split_fl(uint32_t ka, uint32_t kb, uint32_t o[4]) {
  tf2x32(ka, kb, 0u, 0u, o[0], o[1]);  // keys[0]
  tf2x32(ka, kb, 0u, 1u, o[2], o[3]);  // keys[1]
}

extern "C" void kernel_launch(void* const* d_in, const int* in_sizes, int n_in,
                              void* d_out, int out_size, void* d_ws, size_t ws_size,
                              hipStream_t stream) {
  const float* q = (const float*)d_in[0];  // (1,32,128,128)
  const float* k = (const float*)d_in[1];  // (1,32,128,128)
  const float* v = (const float*)d_in[2];  // (4,64,128,128)
  float* out = (float*)d_out;

  uint32_t* ws = (uint32_t*)d_ws;
  uint32_t* pk[2] = { ws, ws + (size_t)KNN * NPIX };
  float* ct[2] = { (float*)(ws + (size_t)2 * KNN * NPIX),
                   (float*)(ws + (size_t)3 * KNN * NPIX) };
  float* wbuf = (float*)(ws + (size_t)4 * KNN * NPIX);
  float* apt  = (float*)(ws + (size_t)5 * KNN * NPIX);
  float* bpt  = apt + (size_t)32 * NPPAD;

  // key chain on host (pure arithmetic; graph-capture safe, deterministic)
  uint32_t sp[4];
  h_split_fl(0u, 42u, sp);                      // split(key(42)) [foldlike]
  uint32_t k0a = sp[0], k0b = sp[1];            // k0  (initial randint key)
  uint32_t kMa = sp[2], kMb = sp[3];            // key (closed over by scan body)

  pad_kernel<<<(32 * NPPAD + 255) / 256, 256, 0, stream>>>(q, k, apt, bpt);

  uint32_t ik[4];
  h_split_fl(k0a, k0b, ik);                     // randint's internal split of k0
  init_kernel<<<(KNN * NPIX) / 256, 256, 0, stream>>>(apt, bpt, pk[0], ct[0],
                                        make_uint4(ik[0], ik[1], ik[2], ik[3]));

  for (int it = 0; it < 10; ++it) {
    uint32_t ka, kb;
    tf2x32(kMa, kMb, 0u, (uint32_t)it, ka, kb); // kk = fold_in(key, it)
    uint4 K[4];
    for (int i = 0; i < 4; ++i) {
      uint32_t ia, ib;
      tf2x32(ka, kb, 0u, (uint32_t)i, ia, ib);  // ki = fold_in(kk, i)
      uint32_t o[4];
      h_split_fl(ia, ib, o);                    // randint's internal split of ki
      K[i] = make_uint4(o[0], o[1], o[2], o[3]);
    }
    step_kernel<<<NPIX, 64, 0, stream>>>(apt, bpt, pk[it & 1], ct[it & 1],
                                         pk[(it + 1) & 1], ct[(it + 1) & 1],
                                         K[0], K[1], K[2], K[3]);
  }

  weights_kernel<<<NPIX / 256, 256, 0, stream>>>(ct[0], wbuf);
  out_kernel<<<(4 * 64 * NPIX) / 256, 256, 0, stream>>>(v, pk[0], wbuf, out);
}